// Round 5
// baseline (91.367 us; speedup 1.0000x reference)
//
#include <hip/hip_runtime.h>
#include <hip/hip_fp16.h>
#include <stdint.h>

// ALCOVE RBF: out[b,e] = exp(-C * sum_d attn[d] * |E[e,d] - X[b,d]|)
// BATCH=2048, NE=2048, ND=128, f32 in/out.
//
// R5: packed-fp16 inner loop at 4 waves/SIMD.
//  - Evidence: v_sad_u32 is quarter-rate (R2=29us == 27.3us quarter-rate
//    floor; R2==R3 despite 4x LDS-traffic difference). All 2-waves/SIMD
//    configs (R1/R3/R4) run 1.5-2.3x above their pipe floors; the
//    4-waves/SIMD config (R2) runs at 1.05x of its floor. So: maximize
//    waves (micro-tile 4x4 -> 4096 waves = 4/SIMD) and minimize inst/term.
//  - Dim-pairs packed in half2: v_pk_add_f16(neg) [sub, 2 terms] +
//    v_and_b32 0x7fff7fff [abs of both halves] + v_pk_add_f16 [acc]
//    = 1.5 inst/term, full-rate -> ~11us VALU floor.
//  - attn >= 0 so attn_d*|x-e| == |attn_d*x - attn_d*e|; scale by attn in
//    f32, then convert to fp16 (RTE). Scaled values <= ~0.08; per-half
//    128/2-term sums <= ~0.7 -> fp16 accumulation error ~1e-4 on dist,
//    output error ~2e-4 << 1.67e-3 threshold.
//  - Whole K (128 dims) staged once: Eh/Xh = 64 dd x 64 rows of uint32
//    (half2) = 16 KB each, 32 KB/block, 4 blocks/CU, ONE barrier total.
//
// Tile: 64(b) x 64(e) per 256-thread block; grid 32x32 = 1024 blocks
// (4/CU). Wave w owns b-rows 16w..16w+15; lane: el=lane&15 -> e=4el..+3
// (b128, 16 distinct addrs, 2-way bank = free, 4-way addr-share =
// broadcast); xg=lane>>4 -> b=16w+4xg..+3 (b128, 4 distinct addrs,
// 16-lane broadcast).

#define ND 128
#define NEC 2048
#define CCONST 6.5f

// acc (half2 pair-sums) += |x - e| elementwise on both halves: 3 full-rate ops.
#define AAH(acc, x, e)                                              \
  {                                                                 \
    uint32_t t_;                                                    \
    asm("v_pk_add_f16 %0, %1, %2 neg_lo:[0,1] neg_hi:[0,1]"         \
        : "=v"(t_) : "v"(x), "v"(e));                               \
    t_ &= 0x7fff7fffu;                                              \
    asm("v_pk_add_f16 %0, %0, %1" : "+v"(acc) : "v"(t_));           \
  }

static __device__ __forceinline__ uint32_t pkh(float lo, float hi) {
  __half2 h = __floats2half2_rn(lo, hi);
  union { __half2 h; uint32_t u; } cv;
  cv.h = h;
  return cv.u;
}

static __device__ __forceinline__ float hsum(uint32_t u) {
  union { uint32_t u; __half2 h; } cv;
  cv.u = u;
  return __half2float(__low2half(cv.h)) + __half2float(__high2half(cv.h));
}

__global__ __launch_bounds__(256, 4)
void alcove_rbf_kernel(const float* __restrict__ X,
                       const float* __restrict__ E,
                       const float* __restrict__ A,
                       float* __restrict__ out) {
  __shared__ uint32_t Eh[64 * 64];  // [dd][e] fp16 dim-pairs, 16 KB
  __shared__ uint32_t Xh[64 * 64];  // [dd][b]                 16 KB

  const int tid = threadIdx.x;
  const int e0 = blockIdx.x * 64;
  const int b0 = blockIdx.y * 64;

  // ---- stage whole K once: scale by attn (f32), pack to fp16 pairs ----
  {
    const int r = tid & 63;          // row within tile (e-row and b-row)
    const int g = tid >> 6;          // dim group: dims 32g..32g+31
    const float4* Ap = reinterpret_cast<const float4*>(A + 32 * g);
    const float4* Ep = reinterpret_cast<const float4*>(E + (size_t)(e0 + r) * ND + 32 * g);
    const float4* Xp = reinterpret_cast<const float4*>(X + (size_t)(b0 + r) * ND + 32 * g);
#pragma unroll
    for (int k = 0; k < 8; ++k) {
      float4 a = Ap[k];
      float4 ev = Ep[k];
      float4 xv = Xp[k];
      int dd = 16 * g + 2 * k;       // dim-pair index
      Eh[dd * 64 + r]       = pkh(ev.x * a.x, ev.y * a.y);
      Eh[(dd + 1) * 64 + r] = pkh(ev.z * a.z, ev.w * a.w);
      Xh[dd * 64 + r]       = pkh(xv.x * a.x, xv.y * a.y);
      Xh[(dd + 1) * 64 + r] = pkh(xv.z * a.z, xv.w * a.w);
    }
  }
  __syncthreads();

  const int lane = tid & 63;
  const int w = tid >> 6;            // wave 0..3 -> b rows 16w..16w+15
  const int el = lane & 15;          // e = e0 + 4*el + i
  const int xg = lane >> 4;          // b = b0 + 16w + 4*xg + j

  uint32_t acc[4][4];
#pragma unroll
  for (int j = 0; j < 4; ++j)
#pragma unroll
    for (int i = 0; i < 4; ++i) acc[j][i] = 0u;

  const uint4* Ev = reinterpret_cast<const uint4*>(Eh);
  const uint4* Xv = reinterpret_cast<const uint4*>(Xh);
  const int xoff = 4 * w + xg;

#pragma unroll 8
  for (int dd = 0; dd < 64; ++dd) {
    uint4 ev = Ev[dd * 16 + el];     // 4 e's, this dim-pair
    uint4 xv = Xv[dd * 16 + xoff];   // 4 b's, this dim-pair (broadcast)
    AAH(acc[0][0], xv.x, ev.x); AAH(acc[0][1], xv.x, ev.y);
    AAH(acc[0][2], xv.x, ev.z); AAH(acc[0][3], xv.x, ev.w);
    AAH(acc[1][0], xv.y, ev.x); AAH(acc[1][1], xv.y, ev.y);
    AAH(acc[1][2], xv.y, ev.z); AAH(acc[1][3], xv.y, ev.w);
    AAH(acc[2][0], xv.z, ev.x); AAH(acc[2][1], xv.z, ev.y);
    AAH(acc[2][2], xv.z, ev.z); AAH(acc[2][3], xv.z, ev.w);
    AAH(acc[3][0], xv.w, ev.x); AAH(acc[3][1], xv.w, ev.y);
    AAH(acc[3][2], xv.w, ev.z); AAH(acc[3][3], xv.w, ev.w);
  }

  // ---- epilogue: dist = lo+hi halves; exp; coalesced float4 stores ----
#pragma unroll
  for (int j = 0; j < 4; ++j) {
    int b = b0 + 16 * w + 4 * xg + j;
    float4 o;
    o.x = __expf(-CCONST * hsum(acc[j][0]));
    o.y = __expf(-CCONST * hsum(acc[j][1]));
    o.z = __expf(-CCONST * hsum(acc[j][2]));
    o.w = __expf(-CCONST * hsum(acc[j][3]));
    reinterpret_cast<float4*>(out + (size_t)b * NEC + e0)[el] = o;
  }
}

extern "C" void kernel_launch(void* const* d_in, const int* in_sizes, int n_in,
                              void* d_out, int out_size, void* d_ws, size_t ws_size,
                              hipStream_t stream) {
  const float* X = (const float*)d_in[0];   // inputs    (2048,128)
  const float* E = (const float*)d_in[1];   // exemplars (2048,128)
  const float* A = (const float*)d_in[2];   // attn      (128,)
  float* out = (float*)d_out;               // (2048,2048)

  dim3 grid(NEC / 64, 2048 / 64);           // (32,32) = 1024 blocks = 4/CU
  dim3 block(256);
  alcove_rbf_kernel<<<grid, block, 0, stream>>>(X, E, A, out);
}

// Round 6
// 85.075 us; speedup vs baseline: 1.0740x; 1.0740x over previous
//
#include <hip/hip_runtime.h>
#include <stdint.h>

// ALCOVE RBF: out[b,e] = exp(-C * sum_d attn[d] * |E[e,d] - X[b,d]|)
// BATCH=2048, NE=2048, ND=128, f32 in/out.
//
// R6: fp32 inner loop inside the EXACT R2 structure.
// Evidence so far: R2 (v_sad_u32, 4 waves/SIMD) = 29us == quarter-rate SAD
// floor (27.3us) at 94% pipe utilization -> 4 waves/SIMD saturates issue and
// SAD is quarter-rate. R4 (fp32 @ 2 waves/SIMD) and R5 (pk_f16, restructured
// staging) both missed their floors -> low occupancy stalls / VOP3P rate
// unknown. The untested cell: full-rate fp32 (2 inst/term, known full rate
// from m07) at 4 waves/SIMD. Floor ~15.5us VALU / ~20.5us LDS-pipe.
//
// attn >= 0 so attn_d*|x-e| == |attn_d*x - attn_d*e|: pre-scale by attn
// during LDS staging; inner loop = v_sub_f32 + v_add_f32 with abs() source
// modifier (asm-pinned so it cannot unfold).
//
// Structure (byte-identical to R2 except float/op): block 256 thr, tile
// 64(b) x 64(e), 4x4 micro-tile/thread, KC=64 chunks, transposed LDS
// [d][row], grid 32x32 = 1024 blocks = 4 blocks/CU = 4 waves/SIMD.

#define BATCH 2048
#define NE 2048
#define ND 128
#define CCONST 6.5f

#define TB 64    // batch tile
#define TE 64    // exemplar tile
#define KC 64    // dim chunk in LDS

// acc += |x - e|; abs as free VOP3 source modifier on a full-rate v_add_f32
#define AA(acc, x, e)                                                  \
  {                                                                    \
    float t_ = (x) - (e);                                              \
    asm("v_add_f32 %0, %0, abs(%1)" : "+v"(acc) : "v"(t_));            \
  }

__global__ __launch_bounds__(256, 4)
void alcove_rbf_kernel(const float* __restrict__ X,
                       const float* __restrict__ E,
                       const float* __restrict__ A,
                       float* __restrict__ out) {
  __shared__ float Xs[KC * TB];  // [d][b]  16 KB
  __shared__ float Es[KC * TE];  // [d][e]  16 KB

  const int tid = threadIdx.x;
  const int e0 = blockIdx.x * TE;   // 32 tiles
  const int b0 = blockIdx.y * TB;   // 32 tiles

  const int tx = tid & 15;          // e dir: 4 e's (4*tx..+3)
  const int ty = tid >> 4;          // b dir: 4 b's (4*ty..+3)
  const int lane_in = tid & 3;

  float acc[4][4];
#pragma unroll
  for (int j = 0; j < 4; ++j)
#pragma unroll
    for (int i = 0; i < 4; ++i) acc[j][i] = 0.f;

  for (int kc = 0; kc < ND; kc += KC) {
    if (kc) __syncthreads();

    const float4* A4 = reinterpret_cast<const float4*>(A + kc);

    // Stage X and E tiles (64 rows x KC dims), transposed to [d][row],
    // pre-scaled by attn. 4 consecutive lanes take 4 consecutive float4s
    // of one row (64B coalesced); transposed LDS writes are 4-way bank
    // conflicted (measured 1.18M cyc total in R2 = negligible).
#pragma unroll
    for (int it = 0; it < 4; ++it) {
      int g = it * 64 + (tid >> 2);     // 0..255
      int row = g & (TB - 1);
      int c4 = 4 * (g >> 6) + lane_in;  // float4 chunk 0..15
      float4 a = A4[c4];
      int dbase = 4 * c4;

      float4 vx = reinterpret_cast<const float4*>(X + (size_t)(b0 + row) * ND + kc)[c4];
      Xs[(dbase + 0) * TB + row] = vx.x * a.x;
      Xs[(dbase + 1) * TB + row] = vx.y * a.y;
      Xs[(dbase + 2) * TB + row] = vx.z * a.z;
      Xs[(dbase + 3) * TB + row] = vx.w * a.w;

      float4 ve = reinterpret_cast<const float4*>(E + (size_t)(e0 + row) * ND + kc)[c4];
      Es[(dbase + 0) * TE + row] = ve.x * a.x;
      Es[(dbase + 1) * TE + row] = ve.y * a.y;
      Es[(dbase + 2) * TE + row] = ve.z * a.z;
      Es[(dbase + 3) * TE + row] = ve.w * a.w;
    }
    __syncthreads();

    const float4* Xs4 = reinterpret_cast<const float4*>(Xs);
    const float4* Es4 = reinterpret_cast<const float4*>(Es);
#pragma unroll 4
    for (int d = 0; d < KC; ++d) {
      // Es4: 16 distinct addrs, 4-lane shared (2-way bank = free);
      // Xs4: 4 distinct addrs, 16-lane broadcast. Proven pattern (R2).
      float4 xv = Xs4[d * (TB / 4) + ty];
      float4 ev = Es4[d * (TE / 4) + tx];
      AA(acc[0][0], xv.x, ev.x); AA(acc[0][1], xv.x, ev.y);
      AA(acc[0][2], xv.x, ev.z); AA(acc[0][3], xv.x, ev.w);
      AA(acc[1][0], xv.y, ev.x); AA(acc[1][1], xv.y, ev.y);
      AA(acc[1][2], xv.y, ev.z); AA(acc[1][3], xv.y, ev.w);
      AA(acc[2][0], xv.z, ev.x); AA(acc[2][1], xv.z, ev.y);
      AA(acc[2][2], xv.z, ev.z); AA(acc[2][3], xv.z, ev.w);
      AA(acc[3][0], xv.w, ev.x); AA(acc[3][1], xv.w, ev.y);
      AA(acc[3][2], xv.w, ev.z); AA(acc[3][3], xv.w, ev.w);
    }
  }

  // ---- epilogue: exp + coalesced float4 stores ----
#pragma unroll
  for (int j = 0; j < 4; ++j) {
    int b = b0 + 4 * ty + j;
    float4 o;
    o.x = __expf(-CCONST * acc[j][0]);
    o.y = __expf(-CCONST * acc[j][1]);
    o.z = __expf(-CCONST * acc[j][2]);
    o.w = __expf(-CCONST * acc[j][3]);
    reinterpret_cast<float4*>(out + (size_t)b * NE + e0)[tx] = o;
  }
}

extern "C" void kernel_launch(void* const* d_in, const int* in_sizes, int n_in,
                              void* d_out, int out_size, void* d_ws, size_t ws_size,
                              hipStream_t stream) {
  const float* X = (const float*)d_in[0];   // inputs    (2048,128)
  const float* E = (const float*)d_in[1];   // exemplars (2048,128)
  const float* A = (const float*)d_in[2];   // attn      (128,)
  float* out = (float*)d_out;               // (2048,2048)

  dim3 grid(NE / TE, BATCH / TB);           // (32,32) = 1024 blocks = 4/CU
  dim3 block(256);
  alcove_rbf_kernel<<<grid, block, 0, stream>>>(X, E, A, out);
}